// Round 5
// baseline (791.114 us; speedup 1.0000x reference)
//
#include <hip/hip_runtime.h>
#include <hip/hip_bf16.h>
#include <stdint.h>

#define BATCH 4
#define NPTS 50000
#define MTOT (BATCH * NPTS)   // 200000 points
#define HID 256
#define NBLK 5
#define CDIM 128

typedef float  floatx4 __attribute__((ext_vector_type(4)));
typedef short  short8  __attribute__((ext_vector_type(8)));

// ---- workspace layout (bytes) ----
#define OFF_WCP   0u           // 5*4*16*512 bf16  = 327,680 B
#define OFF_W0P   327680u      // 5*8*16*512 bf16  = 655,360 B
#define OFF_W1P   983040u      // 655,360 B
#define OFF_GT    1638400u     // 4*32768*32 bf16  = 8,388,608 B
#define OFF_PT    10027008u    // 3*4*16384*32 bf16 = 12,582,912 B
#define OFF_CF    22609920u    // 200000*128 bf16  = 51,200,000 B  (end 73,809,920)

__device__ __forceinline__ unsigned short f2bf(float f) {
  unsigned u = __builtin_bit_cast(unsigned, f);
  u += 0x7fffu + ((u >> 16) & 1u);
  return (unsigned short)(u >> 16);
}
__device__ __forceinline__ unsigned pack2bf(float a, float b) {
  return (unsigned)f2bf(a) | ((unsigned)f2bf(b) << 16);
}
// packed cvt: lowers to v_cvt_pk_bf16_f32 on gfx950; RNE, value-identical to f2bf
__device__ __forceinline__ unsigned pk2(float a, float b) {
  __hip_bfloat162 t = __float22bfloat162_rn(make_float2(a, b));
  unsigned u; __builtin_memcpy(&u, &t, sizeof(u));
  return u;
}

// ---------------- weight prepack: fp32 row-major (K x 256) -> bf16 16x16x32 A-fragment-major ----
// Fragment tile (ks, fm): 512 bf16, entry [l*8+j] = W[ks*32 + (l>>4)*8 + j][fm*16 + (l&15)]
__global__ void pack_weights(const float* __restrict__ Wc, const float* __restrict__ W0,
                             const float* __restrict__ W1,
                             unsigned short* __restrict__ wcp, unsigned short* __restrict__ w0p,
                             unsigned short* __restrict__ w1p) {
  int e = blockIdx.x * 256 + threadIdx.x;
  const int WC_E = NBLK * 32768;   // 163840
  const int W_E  = NBLK * 65536;   // 327680
  const float* src;
  unsigned short* dst;
  int idx, per;
  if (e < WC_E)               { src = Wc; dst = wcp; idx = e;               per = 32768; }
  else if (e < WC_E + W_E)    { src = W0; dst = w0p; idx = e - WC_E;        per = 65536; }
  else                        { src = W1; dst = w1p; idx = e - WC_E - W_E;  per = 65536; }
  int blk = idx / per, r = idx % per;
  int j = r & 7, l = (r >> 3) & 63, tile = r >> 9;
  int fm = tile & 15, ks = tile >> 4;
  int k = ks * 32 + (l >> 4) * 8 + j;
  int n = fm * 16 + (l & 15);
  dst[idx] = f2bf(src[(size_t)blk * per + (size_t)k * 256 + n]);
}

// ---------------- transpose features to channel-last bf16 ----------------
__global__ void transpose_feats(const float* __restrict__ g, const float* __restrict__ xy,
                                const float* __restrict__ yz, const float* __restrict__ xz,
                                unsigned short* __restrict__ gt, unsigned short* __restrict__ pt) {
  int tid = blockIdx.x * 256 + threadIdx.x;
  float v[32];
  unsigned short* dst;
  if (tid < BATCH * 32768) {                 // grid: (B,32,32768) -> (B,32768,32)
    int b = tid >> 15, sp = tid & 32767;
    const float* src = g + ((size_t)b * 32) * 32768 + sp;
#pragma unroll
    for (int c = 0; c < 32; c++) v[c] = src[(size_t)c * 32768];
    dst = gt + (size_t)tid * 32;
  } else {                                   // planes: (3,B,32,16384) -> (3,B,16384,32)
    int t2 = tid - BATCH * 32768;
    int pl = t2 >> 16, rem = t2 & 65535;
    int b = rem >> 14, hw = rem & 16383;
    const float* pp = (pl == 0) ? xy : ((pl == 1) ? yz : xz);
    const float* src = pp + ((size_t)b * 32) * 16384 + hw;
#pragma unroll
    for (int c = 0; c < 32; c++) v[c] = src[(size_t)c * 16384];
    dst = pt + (size_t)t2 * 32;
  }
  uint4* d4 = (uint4*)dst;
#pragma unroll
  for (int i = 0; i < 4; i++) {
    uint4 u;
    u.x = pack2bf(v[i*8+0], v[i*8+1]);
    u.y = pack2bf(v[i*8+2], v[i*8+3]);
    u.z = pack2bf(v[i*8+4], v[i*8+5]);
    u.w = pack2bf(v[i*8+6], v[i*8+7]);
    d4[i] = u;
  }
}

// ---------------- per-point feature interpolation ----------------
__device__ __forceinline__ void acc32(float* acc, const unsigned short* s, float w) {
  const uint4* q = (const uint4*)s;
#pragma unroll
  for (int i = 0; i < 4; i++) {
    uint4 u = q[i];
    acc[i*8+0] += w * __builtin_bit_cast(float, u.x << 16);
    acc[i*8+1] += w * __builtin_bit_cast(float, u.x & 0xffff0000u);
    acc[i*8+2] += w * __builtin_bit_cast(float, u.y << 16);
    acc[i*8+3] += w * __builtin_bit_cast(float, u.y & 0xffff0000u);
    acc[i*8+4] += w * __builtin_bit_cast(float, u.z << 16);
    acc[i*8+5] += w * __builtin_bit_cast(float, u.z & 0xffff0000u);
    acc[i*8+6] += w * __builtin_bit_cast(float, u.w << 16);
    acc[i*8+7] += w * __builtin_bit_cast(float, u.w & 0xffff0000u);
  }
}
__device__ __forceinline__ void store32(unsigned short* dst, const float* a) {
  uint4* d4 = (uint4*)dst;
#pragma unroll
  for (int i = 0; i < 4; i++) {
    uint4 u;
    u.x = pack2bf(a[i*8+0], a[i*8+1]);
    u.y = pack2bf(a[i*8+2], a[i*8+3]);
    u.z = pack2bf(a[i*8+4], a[i*8+5]);
    u.w = pack2bf(a[i*8+6], a[i*8+7]);
    d4[i] = u;
  }
}

__global__ void features(const float* __restrict__ p, const unsigned short* __restrict__ gt,
                         const unsigned short* __restrict__ pt, unsigned short* __restrict__ cf) {
  int m = blockIdx.x * 256 + threadIdx.x;
  if (m >= MTOT) return;
  int b = m / NPTS;
  float px = p[3*m], py = p[3*m+1], pz = p[3*m+2];
  const float inv = 1.0f / 1.101f;       // 1/(1+PAD+1e-3)
  float ux = fminf(fmaxf(px * inv + 0.5f, 0.0f), 1.0f - 1e-5f);
  float uy = fminf(fmaxf(py * inv + 0.5f, 0.0f), 1.0f - 1e-5f);
  float uz = fminf(fmaxf(pz * inv + 0.5f, 0.0f), 1.0f - 1e-5f);

  float acc[32];
  // ---- trilinear grid (x->W fastest, y->H, z->D), res 32 ----
  {
    float fx = ux * 31.f, fy = uy * 31.f, fz = uz * 31.f;
    int x0 = (int)fx, y0 = (int)fy, z0 = (int)fz;
    float wx = fx - x0, wy = fy - y0, wz = fz - z0;
    int x1 = min(x0 + 1, 31), y1 = min(y0 + 1, 31), z1 = min(z0 + 1, 31);
    const unsigned short* gb = gt + ((size_t)b * 32768) * 32;
#pragma unroll
    for (int c = 0; c < 32; c++) acc[c] = 0.f;
    #define GI(z,y,x) (((size_t)(((z)*32 + (y))*32 + (x))) * 32)
    acc32(acc, gb + GI(z0,y0,x0), (1-wx)*(1-wy)*(1-wz));
    acc32(acc, gb + GI(z0,y0,x1), wx*(1-wy)*(1-wz));
    acc32(acc, gb + GI(z0,y1,x0), (1-wx)*wy*(1-wz));
    acc32(acc, gb + GI(z0,y1,x1), wx*wy*(1-wz));
    acc32(acc, gb + GI(z1,y0,x0), (1-wx)*(1-wy)*wz);
    acc32(acc, gb + GI(z1,y0,x1), wx*(1-wy)*wz);
    acc32(acc, gb + GI(z1,y1,x0), (1-wx)*wy*wz);
    acc32(acc, gb + GI(z1,y1,x1), wx*wy*wz);
    store32(cf + (size_t)m * 128, acc);
  }
  // ---- bilinear planes, res 128: xy(u=x,v=y), yz(u=y,v=z), xz(u=x,v=z) ----
  float us[3] = {ux, uy, ux}, vs[3] = {uy, uz, uz};
#pragma unroll
  for (int pl = 0; pl < 3; pl++) {
    float fx = us[pl] * 127.f, fy = vs[pl] * 127.f;
    int x0 = (int)fx, y0 = (int)fy;
    float wx = fx - x0, wy = fy - y0;
    int x1 = min(x0 + 1, 127), y1 = min(y0 + 1, 127);
    const unsigned short* pb = pt + ((size_t)(pl * BATCH + b) * 16384) * 32;
#pragma unroll
    for (int c = 0; c < 32; c++) acc[c] = 0.f;
    acc32(acc, pb + ((size_t)(y0*128 + x0)) * 32, (1-wx)*(1-wy));
    acc32(acc, pb + ((size_t)(y0*128 + x1)) * 32, wx*(1-wy));
    acc32(acc, pb + ((size_t)(y1*128 + x0)) * 32, (1-wx)*wy);
    acc32(acc, pb + ((size_t)(y1*128 + x1)) * 32, wx*wy);
    store32(cf + (size_t)m * 128 + 32 + pl * 32, acc);
  }
}

// ---------------- fused MLP: 16x16x32 MFMA (R3-proven numerics), 8 waves/block ----------------
// Workgroup: 64 points, 512 threads = 8 waves; wave w owns hidden rows [w*32, w*32+32)
// (fm-tiles w*2+0, w*2+1). Identical per-accumulator K-order as the 4-wave R3 kernel ->
// bit-identical GEMM results; only the final cross-wave atomic reduction order differs.
// net_T C-frag: hidden = w*32 + fm*16 + (l>>4)*4 + r ; point = fn*16 + (l&15)
#define ACT_STRIDE 264   // 256 + 8 bf16 pad; 132 dw % 32 = 4 -> uniform free 2-way banking

__global__ __launch_bounds__(512, 2) void mlp(
    const float* __restrict__ p, const float* __restrict__ Wp, const float* __restrict__ bp,
    const float* __restrict__ bc, const float* __restrict__ b0, const float* __restrict__ b1,
    const float* __restrict__ Wout, const float* __restrict__ bout,
    const unsigned short* __restrict__ wcp, const unsigned short* __restrict__ w0p,
    const unsigned short* __restrict__ w1p, const unsigned short* __restrict__ cf,
    float* __restrict__ out) {
  __shared__ __align__(16) unsigned short act [64 * ACT_STRIDE];
  __shared__ __align__(16) unsigned short act2[64 * ACT_STRIDE];
  __shared__ float obuf[64];
  const int tid = threadIdx.x;
  const int w = tid >> 6, l = tid & 63, lq = l >> 4, lr = l & 15;
  const int ptile = blockIdx.x * 64;

  floatx4 net[2][4];   // [fm][fn]; hid tile = w*32 + fm*16

  // ---- init: net = p @ Wp + bp  (float4 loads; hid/4 base = w*8 + fm*4 + lq) ----
  float pv[4][3];
#pragma unroll
  for (int fn = 0; fn < 4; fn++) {
    int pg = ptile + fn * 16 + lr;
    pv[fn][0] = p[pg*3]; pv[fn][1] = p[pg*3+1]; pv[fn][2] = p[pg*3+2];
  }
#pragma unroll
  for (int fm = 0; fm < 2; fm++) {
    int h4 = w*8 + fm*4 + lq;
    float4 w0q = ((const float4*)Wp)[h4];
    float4 w1q = ((const float4*)(Wp + 256))[h4];
    float4 w2q = ((const float4*)(Wp + 512))[h4];
    float4 bq  = ((const float4*)bp)[h4];
    float wq[4][3] = {{w0q.x,w1q.x,w2q.x},{w0q.y,w1q.y,w2q.y},
                      {w0q.z,w1q.z,w2q.z},{w0q.w,w1q.w,w2q.w}};
    float bb[4] = {bq.x, bq.y, bq.z, bq.w};
#pragma unroll
    for (int r = 0; r < 4; r++)
#pragma unroll
      for (int fn = 0; fn < 4; fn++)
        net[fm][fn][r] = bb[r] + pv[fn][0]*wq[r][0] + pv[fn][1]*wq[r][1] + pv[fn][2]*wq[r][2];
  }

  for (int i = 0; i < NBLK; i++) {
    // ---- S1: net += Wc^T . c^T  (K = 128, B-frags straight from global c_feat) ----
    const unsigned short* wcb = wcp + i * 32768;
#pragma unroll
    for (int ks = 0; ks < 4; ks++) {
      short8 af[2], bf[4];
#pragma unroll
      for (int fm = 0; fm < 2; fm++)
        af[fm] = *(const short8*)(wcb + (size_t)(ks*16 + w*2 + fm) * 512 + l*8);
#pragma unroll
      for (int fn = 0; fn < 4; fn++)
        bf[fn] = *(const short8*)(cf + (size_t)(ptile + fn*16 + lr) * 128 + ks*32 + lq*8);
#pragma unroll
      for (int fm = 0; fm < 2; fm++)
#pragma unroll
        for (int fn = 0; fn < 4; fn++)
          net[fm][fn] = __builtin_amdgcn_mfma_f32_16x16x32_bf16(af[fm], bf[fn], net[fm][fn], 0, 0, 0);
    }
    // ---- + bc, stage relu(net) -> act ----
#pragma unroll
    for (int fm = 0; fm < 2; fm++) {
      float4 bq = ((const float4*)(bc + i*256))[w*8 + fm*4 + lq];
      float bb[4] = {bq.x, bq.y, bq.z, bq.w};
#pragma unroll
      for (int fn = 0; fn < 4; fn++) {
#pragma unroll
        for (int r = 0; r < 4; r++) net[fm][fn][r] += bb[r];
        uint2 uu;
        uu.x = pk2(fmaxf(net[fm][fn][0],0.f), fmaxf(net[fm][fn][1],0.f));
        uu.y = pk2(fmaxf(net[fm][fn][2],0.f), fmaxf(net[fm][fn][3],0.f));
        *(uint2*)(&act[(size_t)(fn*16 + lr) * ACT_STRIDE + w*32 + fm*16 + lq*4]) = uu;
      }
    }
    __syncthreads();   // B1: act complete; also fences last iter's act2 reads
    // ---- S2: h = W0^T . relu(net)^T  (K = 256), one 16-hid tile at a time ----
    const unsigned short* w0b = w0p + i * 65536;
#pragma unroll
    for (int fmh = 0; fmh < 2; fmh++) {
      floatx4 h[4];
#pragma unroll
      for (int fn = 0; fn < 4; fn++) h[fn] = (floatx4){0.f,0.f,0.f,0.f};
#pragma unroll
      for (int ks = 0; ks < 8; ks++) {
        short8 af = *(const short8*)(w0b + (size_t)(ks*16 + w*2 + fmh) * 512 + l*8);
        short8 bf[4];
#pragma unroll
        for (int fn = 0; fn < 4; fn++)
          bf[fn] = *(const short8*)(&act[(size_t)(fn*16 + lr) * ACT_STRIDE + ks*32 + lq*8]);
#pragma unroll
        for (int fn = 0; fn < 4; fn++)
          h[fn] = __builtin_amdgcn_mfma_f32_16x16x32_bf16(af, bf[fn], h[fn], 0, 0, 0);
      }
      // ---- + b0, relu -> act2 ----
      float4 bq = ((const float4*)(b0 + i*256))[w*8 + fmh*4 + lq];
      float bb[4] = {bq.x, bq.y, bq.z, bq.w};
#pragma unroll
      for (int fn = 0; fn < 4; fn++) {
        uint2 uu;
        uu.x = pk2(fmaxf(h[fn][0]+bb[0],0.f), fmaxf(h[fn][1]+bb[1],0.f));
        uu.y = pk2(fmaxf(h[fn][2]+bb[2],0.f), fmaxf(h[fn][3]+bb[3],0.f));
        *(uint2*)(&act2[(size_t)(fn*16 + lr) * ACT_STRIDE + w*32 + fmh*16 + lq*4]) = uu;
      }
    }
    __syncthreads();   // B2: act2 complete; also fences this iter's act reads
    // ---- S3: net += W1^T . relu(h)^T + b1 ----
    const unsigned short* w1b = w1p + i * 65536;
#pragma unroll
    for (int ks = 0; ks < 8; ks++) {
      short8 af[2], bf[4];
#pragma unroll
      for (int fm = 0; fm < 2; fm++)
        af[fm] = *(const short8*)(w1b + (size_t)(ks*16 + w*2 + fm) * 512 + l*8);
#pragma unroll
      for (int fn = 0; fn < 4; fn++)
        bf[fn] = *(const short8*)(&act2[(size_t)(fn*16 + lr) * ACT_STRIDE + ks*32 + lq*8]);
#pragma unroll
      for (int fm = 0; fm < 2; fm++)
#pragma unroll
        for (int fn = 0; fn < 4; fn++)
          net[fm][fn] = __builtin_amdgcn_mfma_f32_16x16x32_bf16(af[fm], bf[fn], net[fm][fn], 0, 0, 0);
    }
#pragma unroll
    for (int fm = 0; fm < 2; fm++) {
      float4 bq = ((const float4*)(b1 + i*256))[w*8 + fm*4 + lq];
      float bb[4] = {bq.x, bq.y, bq.z, bq.w};
#pragma unroll
      for (int r = 0; r < 4; r++)
#pragma unroll
        for (int fn = 0; fn < 4; fn++) net[fm][fn][r] += bb[r];
    }
  }

  // ---- out = relu(net) @ Wout + bout ----
  float s[4] = {0.f, 0.f, 0.f, 0.f};
#pragma unroll
  for (int fm = 0; fm < 2; fm++) {
    float4 wq = ((const float4*)Wout)[w*8 + fm*4 + lq];
    float wv[4] = {wq.x, wq.y, wq.z, wq.w};
#pragma unroll
    for (int r = 0; r < 4; r++)
#pragma unroll
      for (int fn = 0; fn < 4; fn++) s[fn] += fmaxf(net[fm][fn][r], 0.f) * wv[r];
  }
#pragma unroll
  for (int fn = 0; fn < 4; fn++) {
    s[fn] += __shfl_xor(s[fn], 16);
    s[fn] += __shfl_xor(s[fn], 32);
  }
  if (tid < 64) obuf[tid] = 0.f;
  __syncthreads();
  if (lq == 0) {
#pragma unroll
    for (int fn = 0; fn < 4; fn++) atomicAdd(&obuf[fn*16 + lr], s[fn]);
  }
  __syncthreads();
  if (tid < 64) out[ptile + tid] = obuf[tid] + bout[0];
}

extern "C" void kernel_launch(void* const* d_in, const int* in_sizes, int n_in,
                              void* d_out, int out_size, void* d_ws, size_t ws_size,
                              hipStream_t stream) {
  const float* p      = (const float*)d_in[0];
  const float* c_grid = (const float*)d_in[1];
  const float* c_xy   = (const float*)d_in[2];
  const float* c_yz   = (const float*)d_in[3];
  const float* c_xz   = (const float*)d_in[4];
  const float* Wp     = (const float*)d_in[5];
  const float* bp     = (const float*)d_in[6];
  const float* Wc     = (const float*)d_in[7];
  const float* bc     = (const float*)d_in[8];
  const float* W0     = (const float*)d_in[9];
  const float* b0     = (const float*)d_in[10];
  const float* W1     = (const float*)d_in[11];
  const float* b1     = (const float*)d_in[12];
  const float* Wout   = (const float*)d_in[13];
  const float* bout   = (const float*)d_in[14];

  char* ws = (char*)d_ws;
  unsigned short* wcp = (unsigned short*)(ws + OFF_WCP);
  unsigned short* w0p = (unsigned short*)(ws + OFF_W0P);
  unsigned short* w1p = (unsigned short*)(ws + OFF_W1P);
  unsigned short* gt  = (unsigned short*)(ws + OFF_GT);
  unsigned short* pt  = (unsigned short*)(ws + OFF_PT);
  unsigned short* cfb = (unsigned short*)(ws + OFF_CF);
  float* out = (float*)d_out;

  pack_weights<<<3200, 256, 0, stream>>>(Wc, W0, W1, wcp, w0p, w1p);
  transpose_feats<<<1280, 256, 0, stream>>>(c_grid, c_xy, c_yz, c_xz, gt, pt);
  features<<<(MTOT + 255) / 256, 256, 0, stream>>>(p, gt, pt, cfb);
  mlp<<<MTOT / 64, 512, 0, stream>>>(p, Wp, bp, bc, b0, b1, Wout, bout, wcp, w0p, w1p, cfb, out);
}

// Round 6
// 759.459 us; speedup vs baseline: 1.0417x; 1.0417x over previous
//
#include <hip/hip_runtime.h>
#include <hip/hip_bf16.h>
#include <stdint.h>

#define BATCH 4
#define NPTS 50000
#define MTOT (BATCH * NPTS)   // 200000 points
#define HID 256
#define NBLK 5
#define CDIM 128

typedef float  floatx4 __attribute__((ext_vector_type(4)));
typedef short  short8  __attribute__((ext_vector_type(8)));

// ---- workspace layout (bytes) ----
#define OFF_WCP   0u           // 5*4*16*512 bf16  = 327,680 B
#define OFF_W0P   327680u      // 5*8*16*512 bf16  = 655,360 B
#define OFF_W1P   983040u      // 655,360 B
#define OFF_GT    1638400u     // 4*32768*32 bf16  = 8,388,608 B
#define OFF_PT    10027008u    // 3*4*16384*32 bf16 = 12,582,912 B  (end 22,609,920)

__device__ __forceinline__ unsigned short f2bf(float f) {
  unsigned u = __builtin_bit_cast(unsigned, f);
  u += 0x7fffu + ((u >> 16) & 1u);
  return (unsigned short)(u >> 16);
}
__device__ __forceinline__ unsigned pack2bf(float a, float b) {
  return (unsigned)f2bf(a) | ((unsigned)f2bf(b) << 16);
}
// packed cvt: lowers to v_cvt_pk_bf16_f32 on gfx950; RNE, value-identical to f2bf
__device__ __forceinline__ unsigned pk2(float a, float b) {
  __hip_bfloat162 t = __float22bfloat162_rn(make_float2(a, b));
  unsigned u; __builtin_memcpy(&u, &t, sizeof(u));
  return u;
}

// ---------------- prep: weight prepack + feature transpose (one launch) ----------------
// pack: fp32 row-major (K x 256) -> bf16 16x16x32 A-fragment-major.
// Fragment tile (ks, fm): 512 bf16, entry [l*8+j] = W[ks*32 + (l>>4)*8 + j][fm*16 + (l&15)]
__global__ void prep(const float* __restrict__ Wc, const float* __restrict__ W0,
                     const float* __restrict__ W1,
                     const float* __restrict__ g, const float* __restrict__ xy,
                     const float* __restrict__ yz, const float* __restrict__ xz,
                     unsigned short* __restrict__ wcp, unsigned short* __restrict__ w0p,
                     unsigned short* __restrict__ w1p,
                     unsigned short* __restrict__ gt, unsigned short* __restrict__ pt) {
  const int bid = blockIdx.x;
  if (bid < 3200) {
    // ---- weight pack: 819,200 elements ----
    int e = bid * 256 + threadIdx.x;
    const int WC_E = NBLK * 32768;   // 163840
    const int W_E  = NBLK * 65536;   // 327680
    const float* src;
    unsigned short* dst;
    int idx, per;
    if (e < WC_E)            { src = Wc; dst = wcp; idx = e;              per = 32768; }
    else if (e < WC_E + W_E) { src = W0; dst = w0p; idx = e - WC_E;       per = 65536; }
    else                     { src = W1; dst = w1p; idx = e - WC_E - W_E; per = 65536; }
    int blk = idx / per, r = idx % per;
    int j = r & 7, l = (r >> 3) & 63, tile = r >> 9;
    int fm = tile & 15, ks = tile >> 4;
    int k = ks * 32 + (l >> 4) * 8 + j;
    int n = fm * 16 + (l & 15);
    dst[idx] = f2bf(src[(size_t)blk * per + (size_t)k * 256 + n]);
    return;
  }
  // ---- feature transpose to channel-last bf16: 327,680 threads ----
  int tid = (bid - 3200) * 256 + threadIdx.x;
  float v[32];
  unsigned short* dst;
  if (tid < BATCH * 32768) {                 // grid: (B,32,32768) -> (B,32768,32)
    int b = tid >> 15, sp = tid & 32767;
    const float* src = g + ((size_t)b * 32) * 32768 + sp;
#pragma unroll
    for (int c = 0; c < 32; c++) v[c] = src[(size_t)c * 32768];
    dst = gt + (size_t)tid * 32;
  } else {                                   // planes: (3,B,32,16384) -> (3,B,16384,32)
    int t2 = tid - BATCH * 32768;
    int pl = t2 >> 16, rem = t2 & 65535;
    int b = rem >> 14, hw = rem & 16383;
    const float* pp = (pl == 0) ? xy : ((pl == 1) ? yz : xz);
    const float* src = pp + ((size_t)b * 32) * 16384 + hw;
#pragma unroll
    for (int c = 0; c < 32; c++) v[c] = src[(size_t)c * 16384];
    dst = pt + (size_t)t2 * 32;
  }
  uint4* d4 = (uint4*)dst;
#pragma unroll
  for (int i = 0; i < 4; i++) {
    uint4 u;
    u.x = pack2bf(v[i*8+0], v[i*8+1]);
    u.y = pack2bf(v[i*8+2], v[i*8+3]);
    u.z = pack2bf(v[i*8+4], v[i*8+5]);
    u.w = pack2bf(v[i*8+6], v[i*8+7]);
    d4[i] = u;
  }
}

// ---------------- interpolation helpers (bit-identical to the old features kernel) ----------
__device__ __forceinline__ void acc32(float* acc, const unsigned short* s, float w) {
  const uint4* q = (const uint4*)s;
#pragma unroll
  for (int i = 0; i < 4; i++) {
    uint4 u = q[i];
    acc[i*8+0] += w * __builtin_bit_cast(float, u.x << 16);
    acc[i*8+1] += w * __builtin_bit_cast(float, u.x & 0xffff0000u);
    acc[i*8+2] += w * __builtin_bit_cast(float, u.y << 16);
    acc[i*8+3] += w * __builtin_bit_cast(float, u.y & 0xffff0000u);
    acc[i*8+4] += w * __builtin_bit_cast(float, u.z << 16);
    acc[i*8+5] += w * __builtin_bit_cast(float, u.z & 0xffff0000u);
    acc[i*8+6] += w * __builtin_bit_cast(float, u.w << 16);
    acc[i*8+7] += w * __builtin_bit_cast(float, u.w & 0xffff0000u);
  }
}
__device__ __forceinline__ void store32_lds(unsigned short* dst, const float* a) {
#pragma unroll
  for (int i = 0; i < 4; i++) {
    uint4 u;
    u.x = pack2bf(a[i*8+0], a[i*8+1]);
    u.y = pack2bf(a[i*8+2], a[i*8+3]);
    u.z = pack2bf(a[i*8+4], a[i*8+5]);
    u.w = pack2bf(a[i*8+6], a[i*8+7]);
    *(uint4*)(dst + i * 8) = u;
  }
}

// ---------------- fused gather + MLP ----------------
// Workgroup: 64 points, 256 threads = 4 waves; wave w owns hidden rows [w*64, w*64+64).
// GEMM op-sequence is bit-identical to the R3 kernel (absmax-proven 0.0314):
//   16x16x32 MFMA, same fragment tiles, same fmh-split fc0, same K-order.
// Changes: cf gathered into persistent LDS (cfb) in the prologue; single act
// buffer with 4 barriers/iter -> ~51 KB LDS -> 3 blocks/CU.
#define ACT_STRIDE 264   // 132 dw % 32 = 4 -> uniform banking
#define CF_STRIDE  136   // 68 dw % 32 = 4  -> same pattern

__global__ __launch_bounds__(256, 3) void mlp(
    const float* __restrict__ p, const float* __restrict__ Wp, const float* __restrict__ bp,
    const float* __restrict__ bc, const float* __restrict__ b0, const float* __restrict__ b1,
    const float* __restrict__ Wout, const float* __restrict__ bout,
    const unsigned short* __restrict__ wcp, const unsigned short* __restrict__ w0p,
    const unsigned short* __restrict__ w1p,
    const unsigned short* __restrict__ gt, const unsigned short* __restrict__ ptab,
    float* __restrict__ out) {
  __shared__ __align__(16) unsigned short act[64 * ACT_STRIDE];
  __shared__ __align__(16) unsigned short cfb[64 * CF_STRIDE];
  __shared__ float obuf[64];
  const int tid = threadIdx.x;
  const int w = tid >> 6, l = tid & 63, lq = l >> 4, lr = l & 15;
  const int ptile = blockIdx.x * 64;

  // ---- gather prologue: 4 threads per point, one feature source each ----
  {
    int pl   = tid & 3;        // 0: grid, 1: xy, 2: yz, 3: xz
    int mloc = tid >> 2;       // 0..63
    int m = ptile + mloc;
    int b = m / NPTS;
    float px = p[3*m], py = p[3*m+1], pz = p[3*m+2];
    const float inv = 1.0f / 1.101f;       // 1/(1+PAD+1e-3)
    float ux = fminf(fmaxf(px * inv + 0.5f, 0.0f), 1.0f - 1e-5f);
    float uy = fminf(fmaxf(py * inv + 0.5f, 0.0f), 1.0f - 1e-5f);
    float uz = fminf(fmaxf(pz * inv + 0.5f, 0.0f), 1.0f - 1e-5f);
    float acc[32];
#pragma unroll
    for (int c = 0; c < 32; c++) acc[c] = 0.f;
    if (pl == 0) {
      // trilinear grid (x->W fastest), res 32
      float fx = ux * 31.f, fy = uy * 31.f, fz = uz * 31.f;
      int x0 = (int)fx, y0 = (int)fy, z0 = (int)fz;
      float wx = fx - x0, wy = fy - y0, wz = fz - z0;
      int x1 = min(x0 + 1, 31), y1 = min(y0 + 1, 31), z1 = min(z0 + 1, 31);
      const unsigned short* gb = gt + ((size_t)b * 32768) * 32;
      #define GI(z,y,x) (((size_t)(((z)*32 + (y))*32 + (x))) * 32)
      acc32(acc, gb + GI(z0,y0,x0), (1-wx)*(1-wy)*(1-wz));
      acc32(acc, gb + GI(z0,y0,x1), wx*(1-wy)*(1-wz));
      acc32(acc, gb + GI(z0,y1,x0), (1-wx)*wy*(1-wz));
      acc32(acc, gb + GI(z0,y1,x1), wx*wy*(1-wz));
      acc32(acc, gb + GI(z1,y0,x0), (1-wx)*(1-wy)*wz);
      acc32(acc, gb + GI(z1,y0,x1), wx*(1-wy)*wz);
      acc32(acc, gb + GI(z1,y1,x0), (1-wx)*wy*wz);
      acc32(acc, gb + GI(z1,y1,x1), wx*wy*wz);
    } else {
      // bilinear plane, res 128: xy(u=x,v=y), yz(u=y,v=z), xz(u=x,v=z)
      float uu = (pl == 2) ? uy : ux;
      float vv = (pl == 1) ? uy : uz;
      float fx = uu * 127.f, fy = vv * 127.f;
      int x0 = (int)fx, y0 = (int)fy;
      float wx = fx - x0, wy = fy - y0;
      int x1 = min(x0 + 1, 127), y1 = min(y0 + 1, 127);
      const unsigned short* pb = ptab + ((size_t)((pl - 1) * BATCH + b) * 16384) * 32;
      acc32(acc, pb + ((size_t)(y0*128 + x0)) * 32, (1-wx)*(1-wy));
      acc32(acc, pb + ((size_t)(y0*128 + x1)) * 32, wx*(1-wy));
      acc32(acc, pb + ((size_t)(y1*128 + x0)) * 32, (1-wx)*wy);
      acc32(acc, pb + ((size_t)(y1*128 + x1)) * 32, wx*wy);
    }
    store32_lds(&cfb[(size_t)mloc * CF_STRIDE + pl * 32], acc);
  }

  floatx4 net[4][4];   // [fm][fn]; hidden = w*64 + fm*16 + lq*4 + r ; point = fn*16 + lr

  // ---- init: net = p @ Wp + bp  (overlaps the gather's LDS latency) ----
  float pv[4][3];
#pragma unroll
  for (int fn = 0; fn < 4; fn++) {
    int pg = ptile + fn * 16 + lr;
    pv[fn][0] = p[pg*3]; pv[fn][1] = p[pg*3+1]; pv[fn][2] = p[pg*3+2];
  }
#pragma unroll
  for (int fm = 0; fm < 4; fm++) {
    int h4 = w*16 + fm*4 + lq;
    float4 w0q = ((const float4*)Wp)[h4];
    float4 w1q = ((const float4*)(Wp + 256))[h4];
    float4 w2q = ((const float4*)(Wp + 512))[h4];
    float4 bq  = ((const float4*)bp)[h4];
    float wq[4][3] = {{w0q.x,w1q.x,w2q.x},{w0q.y,w1q.y,w2q.y},
                      {w0q.z,w1q.z,w2q.z},{w0q.w,w1q.w,w2q.w}};
    float bb[4] = {bq.x, bq.y, bq.z, bq.w};
#pragma unroll
    for (int r = 0; r < 4; r++)
#pragma unroll
      for (int fn = 0; fn < 4; fn++)
        net[fm][fn][r] = bb[r] + pv[fn][0]*wq[r][0] + pv[fn][1]*wq[r][1] + pv[fn][2]*wq[r][2];
  }
  __syncthreads();   // cfb ready

  for (int i = 0; i < NBLK; i++) {
    // ---- S1: net += Wc^T . c^T  (K = 128, B-frags from LDS cfb) ----
    const unsigned short* wcb = wcp + i * 32768;
#pragma unroll
    for (int ks = 0; ks < 4; ks++) {
      short8 af[4], bf[4];
#pragma unroll
      for (int fm = 0; fm < 4; fm++)
        af[fm] = *(const short8*)(wcb + (size_t)(ks*16 + w*4 + fm) * 512 + l*8);
#pragma unroll
      for (int fn = 0; fn < 4; fn++)
        bf[fn] = *(const short8*)(&cfb[(size_t)(fn*16 + lr) * CF_STRIDE + ks*32 + lq*8]);
#pragma unroll
      for (int fm = 0; fm < 4; fm++)
#pragma unroll
        for (int fn = 0; fn < 4; fn++)
          net[fm][fn] = __builtin_amdgcn_mfma_f32_16x16x32_bf16(af[fm], bf[fn], net[fm][fn], 0, 0, 0);
    }
    // ---- + bc (in regs) ----
#pragma unroll
    for (int fm = 0; fm < 4; fm++) {
      float4 bq = ((const float4*)(bc + i*256))[w*16 + fm*4 + lq];
      float bb[4] = {bq.x, bq.y, bq.z, bq.w};
#pragma unroll
      for (int fn = 0; fn < 4; fn++)
#pragma unroll
        for (int r = 0; r < 4; r++) net[fm][fn][r] += bb[r];
    }
    __syncthreads();   // B0: previous iteration's S3 reads of act are done
    // ---- write relu(net) -> act ----
#pragma unroll
    for (int fm = 0; fm < 4; fm++)
#pragma unroll
      for (int fn = 0; fn < 4; fn++) {
        uint2 uu;
        uu.x = pk2(fmaxf(net[fm][fn][0],0.f), fmaxf(net[fm][fn][1],0.f));
        uu.y = pk2(fmaxf(net[fm][fn][2],0.f), fmaxf(net[fm][fn][3],0.f));
        *(uint2*)(&act[(size_t)(fn*16 + lr) * ACT_STRIDE + w*64 + fm*16 + lq*4]) = uu;
      }
    __syncthreads();   // B1: act = relu(net) complete
    // ---- S2: h = W0^T . relu(net)^T  (K = 256), fmh-split; stash packed relu(h) ----
    const unsigned short* w0b = w0p + i * 65536;
    uint2 st[2][2][4];
#pragma unroll
    for (int fmh = 0; fmh < 2; fmh++) {
      floatx4 h[2][4];
#pragma unroll
      for (int fm2 = 0; fm2 < 2; fm2++)
#pragma unroll
        for (int fn = 0; fn < 4; fn++) h[fm2][fn] = (floatx4){0.f,0.f,0.f,0.f};
#pragma unroll
      for (int ks = 0; ks < 8; ks++) {
        short8 af[2], bf[4];
#pragma unroll
        for (int fm2 = 0; fm2 < 2; fm2++)
          af[fm2] = *(const short8*)(w0b + (size_t)(ks*16 + w*4 + fmh*2 + fm2) * 512 + l*8);
#pragma unroll
        for (int fn = 0; fn < 4; fn++)
          bf[fn] = *(const short8*)(&act[(size_t)(fn*16 + lr) * ACT_STRIDE + ks*32 + lq*8]);
#pragma unroll
        for (int fm2 = 0; fm2 < 2; fm2++)
#pragma unroll
          for (int fn = 0; fn < 4; fn++)
            h[fm2][fn] = __builtin_amdgcn_mfma_f32_16x16x32_bf16(af[fm2], bf[fn], h[fm2][fn], 0, 0, 0);
      }
#pragma unroll
      for (int fm2 = 0; fm2 < 2; fm2++) {
        int fmg = fmh*2 + fm2;
        float4 bq = ((const float4*)(b0 + i*256))[w*16 + fmg*4 + lq];
        float bb[4] = {bq.x, bq.y, bq.z, bq.w};
#pragma unroll
        for (int fn = 0; fn < 4; fn++) {
          st[fmh][fm2][fn].x = pk2(fmaxf(h[fm2][fn][0]+bb[0],0.f), fmaxf(h[fm2][fn][1]+bb[1],0.f));
          st[fmh][fm2][fn].y = pk2(fmaxf(h[fm2][fn][2]+bb[2],0.f), fmaxf(h[fm2][fn][3]+bb[3],0.f));
        }
      }
    }
    __syncthreads();   // B2: all S2 reads of act are done
    // ---- write relu(h) -> act ----
#pragma unroll
    for (int fmh = 0; fmh < 2; fmh++)
#pragma unroll
      for (int fm2 = 0; fm2 < 2; fm2++) {
        int fmg = fmh*2 + fm2;
#pragma unroll
        for (int fn = 0; fn < 4; fn++)
          *(uint2*)(&act[(size_t)(fn*16 + lr) * ACT_STRIDE + w*64 + fmg*16 + lq*4]) = st[fmh][fm2][fn];
      }
    __syncthreads();   // B3: act = relu(h) complete
    // ---- S3: net += W1^T . relu(h)^T + b1 ----
    const unsigned short* w1b = w1p + i * 65536;
#pragma unroll
    for (int ks = 0; ks < 8; ks++) {
      short8 af[4], bf[4];
#pragma unroll
      for (int fm = 0; fm < 4; fm++)
        af[fm] = *(const short8*)(w1b + (size_t)(ks*16 + w*4 + fm) * 512 + l*8);
#pragma unroll
      for (int fn = 0; fn < 4; fn++)
        bf[fn] = *(const short8*)(&act[(size_t)(fn*16 + lr) * ACT_STRIDE + ks*32 + lq*8]);
#pragma unroll
      for (int fm = 0; fm < 4; fm++)
#pragma unroll
        for (int fn = 0; fn < 4; fn++)
          net[fm][fn] = __builtin_amdgcn_mfma_f32_16x16x32_bf16(af[fm], bf[fn], net[fm][fn], 0, 0, 0);
    }
#pragma unroll
    for (int fm = 0; fm < 4; fm++) {
      float4 bq = ((const float4*)(b1 + i*256))[w*16 + fm*4 + lq];
      float bb[4] = {bq.x, bq.y, bq.z, bq.w};
#pragma unroll
      for (int r = 0; r < 4; r++)
#pragma unroll
        for (int fn = 0; fn < 4; fn++) net[fm][fn][r] += bb[r];
    }
  }

  // ---- out = relu(net) @ Wout + bout ----
  float s[4] = {0.f, 0.f, 0.f, 0.f};
#pragma unroll
  for (int fm = 0; fm < 4; fm++) {
    float4 wq = ((const float4*)Wout)[w*16 + fm*4 + lq];
    float wv[4] = {wq.x, wq.y, wq.z, wq.w};
#pragma unroll
    for (int r = 0; r < 4; r++)
#pragma unroll
      for (int fn = 0; fn < 4; fn++) s[fn] += fmaxf(net[fm][fn][r], 0.f) * wv[r];
  }
#pragma unroll
  for (int fn = 0; fn < 4; fn++) {
    s[fn] += __shfl_xor(s[fn], 16);
    s[fn] += __shfl_xor(s[fn], 32);
  }
  if (tid < 64) obuf[tid] = 0.f;
  __syncthreads();
  if (lq == 0) {
#pragma unroll
    for (int fn = 0; fn < 4; fn++) atomicAdd(&obuf[fn*16 + lr], s[fn]);
  }
  __syncthreads();
  if (tid < 64) out[ptile + tid] = obuf[tid] + bout[0];
}

extern "C" void kernel_launch(void* const* d_in, const int* in_sizes, int n_in,
                              void* d_out, int out_size, void* d_ws, size_t ws_size,
                              hipStream_t stream) {
  const float* p      = (const float*)d_in[0];
  const float* c_grid = (const float*)d_in[1];
  const float* c_xy   = (const float*)d_in[2];
  const float* c_yz   = (const float*)d_in[3];
  const float* c_xz   = (const float*)d_in[4];
  const float* Wp     = (const float*)d_in[5];
  const float* bp     = (const float*)d_in[6];
  const float* Wc     = (const float*)d_in[7];
  const float* bc     = (const float*)d_in[8];
  const float* W0     = (const float*)d_in[9];
  const float* b0     = (const float*)d_in[10];
  const float* W1     = (const float*)d_in[11];
  const float* b1     = (const float*)d_in[12];
  const float* Wout   = (const float*)d_in[13];
  const float* bout   = (const float*)d_in[14];

  char* ws = (char*)d_ws;
  unsigned short* wcp = (unsigned short*)(ws + OFF_WCP);
  unsigned short* w0p = (unsigned short*)(ws + OFF_W0P);
  unsigned short* w1p = (unsigned short*)(ws + OFF_W1P);
  unsigned short* gt  = (unsigned short*)(ws + OFF_GT);
  unsigned short* pt  = (unsigned short*)(ws + OFF_PT);
  float* out = (float*)d_out;

  prep<<<4480, 256, 0, stream>>>(Wc, W0, W1, c_grid, c_xy, c_yz, c_xz,
                                 wcp, w0p, w1p, gt, pt);
  mlp<<<MTOT / 64, 256, 0, stream>>>(p, Wp, bp, bc, b0, b1, Wout, bout,
                                     wcp, w0p, w1p, gt, pt, out);
}

// Round 7
// 576.128 us; speedup vs baseline: 1.3732x; 1.3182x over previous
//
#include <hip/hip_runtime.h>
#include <hip/hip_bf16.h>
#include <stdint.h>

#define BATCH 4
#define NPTS 50000
#define MTOT (BATCH * NPTS)   // 200000 points
#define HID 256
#define NBLK 5
#define CDIM 128

typedef float  floatx4 __attribute__((ext_vector_type(4)));
typedef short  short8  __attribute__((ext_vector_type(8)));

// ---- workspace layout (bytes) ----
#define OFF_WCP   0u           // 5*4*16*512 bf16  = 327,680 B
#define OFF_W0P   327680u      // 5*8*16*512 bf16  = 655,360 B
#define OFF_W1P   983040u      // 655,360 B
#define OFF_GT    1638400u     // 4*32768*32 bf16  = 8,388,608 B
#define OFF_PT    10027008u    // 3*4*16384*32 bf16 = 12,582,912 B  (end 22,609,920)

__device__ __forceinline__ unsigned short f2bf(float f) {
  unsigned u = __builtin_bit_cast(unsigned, f);
  u += 0x7fffu + ((u >> 16) & 1u);
  return (unsigned short)(u >> 16);
}
__device__ __forceinline__ unsigned pack2bf(float a, float b) {
  return (unsigned)f2bf(a) | ((unsigned)f2bf(b) << 16);
}
// packed cvt: lowers to v_cvt_pk_bf16_f32 on gfx950; RNE, value-identical to f2bf
__device__ __forceinline__ unsigned pk2(float a, float b) {
  __hip_bfloat162 t = __float22bfloat162_rn(make_float2(a, b));
  unsigned u; __builtin_memcpy(&u, &t, sizeof(u));
  return u;
}

// ---------------- prep: weight prepack + feature transpose (one launch) ----------------
// pack: fp32 row-major (K x 256) -> bf16 16x16x32 A-fragment-major.
// Fragment tile (ks, fm): 512 bf16, entry [l*8+j] = W[ks*32 + (l>>4)*8 + j][fm*16 + (l&15)]
__global__ void prep(const float* __restrict__ Wc, const float* __restrict__ W0,
                     const float* __restrict__ W1,
                     const float* __restrict__ g, const float* __restrict__ xy,
                     const float* __restrict__ yz, const float* __restrict__ xz,
                     unsigned short* __restrict__ wcp, unsigned short* __restrict__ w0p,
                     unsigned short* __restrict__ w1p,
                     unsigned short* __restrict__ gt, unsigned short* __restrict__ pt) {
  const int bid = blockIdx.x;
  if (bid < 3200) {
    // ---- weight pack: 819,200 elements ----
    int e = bid * 256 + threadIdx.x;
    const int WC_E = NBLK * 32768;   // 163840
    const int W_E  = NBLK * 65536;   // 327680
    const float* src;
    unsigned short* dst;
    int idx, per;
    if (e < WC_E)            { src = Wc; dst = wcp; idx = e;              per = 32768; }
    else if (e < WC_E + W_E) { src = W0; dst = w0p; idx = e - WC_E;       per = 65536; }
    else                     { src = W1; dst = w1p; idx = e - WC_E - W_E; per = 65536; }
    int blk = idx / per, r = idx % per;
    int j = r & 7, l = (r >> 3) & 63, tile = r >> 9;
    int fm = tile & 15, ks = tile >> 4;
    int k = ks * 32 + (l >> 4) * 8 + j;
    int n = fm * 16 + (l & 15);
    dst[idx] = f2bf(src[(size_t)blk * per + (size_t)k * 256 + n]);
    return;
  }
  // ---- feature transpose to channel-last bf16: 327,680 threads ----
  int tid = (bid - 3200) * 256 + threadIdx.x;
  float v[32];
  unsigned short* dst;
  if (tid < BATCH * 32768) {                 // grid: (B,32,32768) -> (B,32768,32)
    int b = tid >> 15, sp = tid & 32767;
    const float* src = g + ((size_t)b * 32) * 32768 + sp;
#pragma unroll
    for (int c = 0; c < 32; c++) v[c] = src[(size_t)c * 32768];
    dst = gt + (size_t)tid * 32;
  } else {                                   // planes: (3,B,32,16384) -> (3,B,16384,32)
    int t2 = tid - BATCH * 32768;
    int pl = t2 >> 16, rem = t2 & 65535;
    int b = rem >> 14, hw = rem & 16383;
    const float* pp = (pl == 0) ? xy : ((pl == 1) ? yz : xz);
    const float* src = pp + ((size_t)b * 32) * 16384 + hw;
#pragma unroll
    for (int c = 0; c < 32; c++) v[c] = src[(size_t)c * 16384];
    dst = pt + (size_t)t2 * 32;
  }
  uint4* d4 = (uint4*)dst;
#pragma unroll
  for (int i = 0; i < 4; i++) {
    uint4 u;
    u.x = pack2bf(v[i*8+0], v[i*8+1]);
    u.y = pack2bf(v[i*8+2], v[i*8+3]);
    u.z = pack2bf(v[i*8+4], v[i*8+5]);
    u.w = pack2bf(v[i*8+6], v[i*8+7]);
    d4[i] = u;
  }
}

// ---------------- interpolation helpers (bit-identical to the R3 features kernel) ----------
__device__ __forceinline__ void acc32(float* acc, const unsigned short* s, float w) {
  const uint4* q = (const uint4*)s;
#pragma unroll
  for (int i = 0; i < 4; i++) {
    uint4 u = q[i];
    acc[i*8+0] += w * __builtin_bit_cast(float, u.x << 16);
    acc[i*8+1] += w * __builtin_bit_cast(float, u.x & 0xffff0000u);
    acc[i*8+2] += w * __builtin_bit_cast(float, u.y << 16);
    acc[i*8+3] += w * __builtin_bit_cast(float, u.y & 0xffff0000u);
    acc[i*8+4] += w * __builtin_bit_cast(float, u.z << 16);
    acc[i*8+5] += w * __builtin_bit_cast(float, u.z & 0xffff0000u);
    acc[i*8+6] += w * __builtin_bit_cast(float, u.w << 16);
    acc[i*8+7] += w * __builtin_bit_cast(float, u.w & 0xffff0000u);
  }
}
__device__ __forceinline__ void store32_lds(unsigned short* dst, const float* a) {
#pragma unroll
  for (int i = 0; i < 4; i++) {
    uint4 u;
    u.x = pack2bf(a[i*8+0], a[i*8+1]);
    u.y = pack2bf(a[i*8+2], a[i*8+3]);
    u.z = pack2bf(a[i*8+4], a[i*8+5]);
    u.w = pack2bf(a[i*8+6], a[i*8+7]);
    *(uint4*)(dst + i * 8) = u;
  }
}

// ---------------- fused gather + MLP ----------------
// Workgroup: 64 points, 256 threads = 4 waves; wave w owns hidden rows [w*64, w*64+64).
// K-loop = R3's proven 2-buffer / 2-barrier structure (mlp 411 us, no spills).
// New: gather staged in LDS overlaid on `act`, then cf B-fragments hoisted to 64
// persistent VGPRs per lane -> S1 has zero memory reads for B; no global cf buffer.
// Registers: cfB 64 + net 64 (AGPR) + S2 transients ~56 -> ~184 total -> 2 waves/EU.
#define ACT_STRIDE 264   // 132 dw % 32 = 4 -> uniform free 2-way banking
#define CF_STRIDE  136   // 68 dw % 32 = 4  -> same pattern (staging only)

__global__ __launch_bounds__(256, 2) void mlp(
    const float* __restrict__ p, const float* __restrict__ Wp, const float* __restrict__ bp,
    const float* __restrict__ bc, const float* __restrict__ b0, const float* __restrict__ b1,
    const float* __restrict__ Wout, const float* __restrict__ bout,
    const unsigned short* __restrict__ wcp, const unsigned short* __restrict__ w0p,
    const unsigned short* __restrict__ w1p,
    const unsigned short* __restrict__ gt, const unsigned short* __restrict__ ptab,
    float* __restrict__ out) {
  __shared__ __align__(16) unsigned short act [64 * ACT_STRIDE];
  __shared__ __align__(16) unsigned short act2[64 * ACT_STRIDE];
  __shared__ float obuf[64];
  const int tid = threadIdx.x;
  const int w = tid >> 6, l = tid & 63, lq = l >> 4, lr = l & 15;
  const int ptile = blockIdx.x * 64;

  // ---- gather prologue: 4 threads per point, one feature source each; stage into act ----
  {
    int pl   = tid & 3;        // 0: grid, 1: xy, 2: yz, 3: xz
    int mloc = tid >> 2;       // 0..63
    int m = ptile + mloc;
    int b = m / NPTS;
    float px = p[3*m], py = p[3*m+1], pz = p[3*m+2];
    const float inv = 1.0f / 1.101f;       // 1/(1+PAD+1e-3)
    float ux = fminf(fmaxf(px * inv + 0.5f, 0.0f), 1.0f - 1e-5f);
    float uy = fminf(fmaxf(py * inv + 0.5f, 0.0f), 1.0f - 1e-5f);
    float uz = fminf(fmaxf(pz * inv + 0.5f, 0.0f), 1.0f - 1e-5f);
    float acc[32];
#pragma unroll
    for (int c = 0; c < 32; c++) acc[c] = 0.f;
    if (pl == 0) {
      // trilinear grid (x->W fastest), res 32
      float fx = ux * 31.f, fy = uy * 31.f, fz = uz * 31.f;
      int x0 = (int)fx, y0 = (int)fy, z0 = (int)fz;
      float wx = fx - x0, wy = fy - y0, wz = fz - z0;
      int x1 = min(x0 + 1, 31), y1 = min(y0 + 1, 31), z1 = min(z0 + 1, 31);
      const unsigned short* gb = gt + ((size_t)b * 32768) * 32;
      #define GI(z,y,x) (((size_t)(((z)*32 + (y))*32 + (x))) * 32)
      acc32(acc, gb + GI(z0,y0,x0), (1-wx)*(1-wy)*(1-wz));
      acc32(acc, gb + GI(z0,y0,x1), wx*(1-wy)*(1-wz));
      acc32(acc, gb + GI(z0,y1,x0), (1-wx)*wy*(1-wz));
      acc32(acc, gb + GI(z0,y1,x1), wx*wy*(1-wz));
      acc32(acc, gb + GI(z1,y0,x0), (1-wx)*(1-wy)*wz);
      acc32(acc, gb + GI(z1,y0,x1), wx*(1-wy)*wz);
      acc32(acc, gb + GI(z1,y1,x0), (1-wx)*wy*wz);
      acc32(acc, gb + GI(z1,y1,x1), wx*wy*wz);
    } else {
      // bilinear plane, res 128: xy(u=x,v=y), yz(u=y,v=z), xz(u=x,v=z)
      float uu = (pl == 2) ? uy : ux;
      float vv = (pl == 1) ? uy : uz;
      float fx = uu * 127.f, fy = vv * 127.f;
      int x0 = (int)fx, y0 = (int)fy;
      float wx = fx - x0, wy = fy - y0;
      int x1 = min(x0 + 1, 127), y1 = min(y0 + 1, 127);
      const unsigned short* pb = ptab + ((size_t)((pl - 1) * BATCH + b) * 16384) * 32;
      acc32(acc, pb + ((size_t)(y0*128 + x0)) * 32, (1-wx)*(1-wy));
      acc32(acc, pb + ((size_t)(y0*128 + x1)) * 32, wx*(1-wy));
      acc32(acc, pb + ((size_t)(y1*128 + x0)) * 32, (1-wx)*wy);
      acc32(acc, pb + ((size_t)(y1*128 + x1)) * 32, wx*wy);
    }
    store32_lds(&act[(size_t)mloc * CF_STRIDE + pl * 32], acc);
  }
  __syncthreads();   // cf staging complete

  // ---- hoist cf B-fragments into persistent registers (identical for every wave) ----
  short8 cfB[4][4];   // [fn][ks]
#pragma unroll
  for (int fn = 0; fn < 4; fn++)
#pragma unroll
    for (int ks = 0; ks < 4; ks++)
      cfB[fn][ks] = *(const short8*)(&act[(size_t)(fn*16 + lr) * CF_STRIDE + ks*32 + lq*8]);

  floatx4 net[4][4];   // [fm][fn]; hidden = w*64 + fm*16 + lq*4 + r ; point = fn*16 + lr

  // ---- init: net = p @ Wp + bp ----
  float pv[4][3];
#pragma unroll
  for (int fn = 0; fn < 4; fn++) {
    int pg = ptile + fn * 16 + lr;
    pv[fn][0] = p[pg*3]; pv[fn][1] = p[pg*3+1]; pv[fn][2] = p[pg*3+2];
  }
#pragma unroll
  for (int fm = 0; fm < 4; fm++) {
    int h4 = w*16 + fm*4 + lq;
    float4 w0q = ((const float4*)Wp)[h4];
    float4 w1q = ((const float4*)(Wp + 256))[h4];
    float4 w2q = ((const float4*)(Wp + 512))[h4];
    float4 bq  = ((const float4*)bp)[h4];
    float wq[4][3] = {{w0q.x,w1q.x,w2q.x},{w0q.y,w1q.y,w2q.y},
                      {w0q.z,w1q.z,w2q.z},{w0q.w,w1q.w,w2q.w}};
    float bb[4] = {bq.x, bq.y, bq.z, bq.w};
#pragma unroll
    for (int r = 0; r < 4; r++)
#pragma unroll
      for (int fn = 0; fn < 4; fn++)
        net[fm][fn][r] = bb[r] + pv[fn][0]*wq[r][0] + pv[fn][1]*wq[r][1] + pv[fn][2]*wq[r][2];
  }
  __syncthreads();   // all staging reads done; act is free for the K-loop

  for (int i = 0; i < NBLK; i++) {
    // ---- S1: net += Wc^T . c^T  (K = 128, B-frags in registers) ----
    const unsigned short* wcb = wcp + i * 32768;
#pragma unroll
    for (int ks = 0; ks < 4; ks++) {
      short8 af[4];
#pragma unroll
      for (int fm = 0; fm < 4; fm++)
        af[fm] = *(const short8*)(wcb + (size_t)(ks*16 + w*4 + fm) * 512 + l*8);
#pragma unroll
      for (int fm = 0; fm < 4; fm++)
#pragma unroll
        for (int fn = 0; fn < 4; fn++)
          net[fm][fn] = __builtin_amdgcn_mfma_f32_16x16x32_bf16(af[fm], cfB[fn][ks], net[fm][fn], 0, 0, 0);
    }
    // ---- + bc, stage relu(net) -> act  (prev iter's S2 act-reads fenced by prev B2) ----
#pragma unroll
    for (int fm = 0; fm < 4; fm++) {
      float4 bq = ((const float4*)(bc + i*256))[w*16 + fm*4 + lq];
      float bb[4] = {bq.x, bq.y, bq.z, bq.w};
#pragma unroll
      for (int fn = 0; fn < 4; fn++) {
#pragma unroll
        for (int r = 0; r < 4; r++) net[fm][fn][r] += bb[r];
        uint2 uu;
        uu.x = pk2(fmaxf(net[fm][fn][0],0.f), fmaxf(net[fm][fn][1],0.f));
        uu.y = pk2(fmaxf(net[fm][fn][2],0.f), fmaxf(net[fm][fn][3],0.f));
        *(uint2*)(&act[(size_t)(fn*16 + lr) * ACT_STRIDE + w*64 + fm*16 + lq*4]) = uu;
      }
    }
    __syncthreads();   // B1: act complete; also fences last iter's act2 reads
    // ---- S2: h = W0^T . relu(net)^T  (K = 256), fmh-split; write relu(h) -> act2 ----
    const unsigned short* w0b = w0p + i * 65536;
#pragma unroll
    for (int fmh = 0; fmh < 2; fmh++) {
      floatx4 h[2][4];
#pragma unroll
      for (int fm2 = 0; fm2 < 2; fm2++)
#pragma unroll
        for (int fn = 0; fn < 4; fn++) h[fm2][fn] = (floatx4){0.f,0.f,0.f,0.f};
#pragma unroll
      for (int ks = 0; ks < 8; ks++) {
        short8 af[2], bf[4];
#pragma unroll
        for (int fm2 = 0; fm2 < 2; fm2++)
          af[fm2] = *(const short8*)(w0b + (size_t)(ks*16 + w*4 + fmh*2 + fm2) * 512 + l*8);
#pragma unroll
        for (int fn = 0; fn < 4; fn++)
          bf[fn] = *(const short8*)(&act[(size_t)(fn*16 + lr) * ACT_STRIDE + ks*32 + lq*8]);
#pragma unroll
        for (int fm2 = 0; fm2 < 2; fm2++)
#pragma unroll
          for (int fn = 0; fn < 4; fn++)
            h[fm2][fn] = __builtin_amdgcn_mfma_f32_16x16x32_bf16(af[fm2], bf[fn], h[fm2][fn], 0, 0, 0);
      }
#pragma unroll
      for (int fm2 = 0; fm2 < 2; fm2++) {
        int fmg = fmh*2 + fm2;
        float4 bq = ((const float4*)(b0 + i*256))[w*16 + fmg*4 + lq];
        float bb[4] = {bq.x, bq.y, bq.z, bq.w};
#pragma unroll
        for (int fn = 0; fn < 4; fn++) {
          uint2 uu;
          uu.x = pk2(fmaxf(h[fm2][fn][0]+bb[0],0.f), fmaxf(h[fm2][fn][1]+bb[1],0.f));
          uu.y = pk2(fmaxf(h[fm2][fn][2]+bb[2],0.f), fmaxf(h[fm2][fn][3]+bb[3],0.f));
          *(uint2*)(&act2[(size_t)(fn*16 + lr) * ACT_STRIDE + w*64 + fmg*16 + lq*4]) = uu;
        }
      }
    }
    __syncthreads();   // B2: act2 complete; also fences this iter's act reads
    // ---- S3: net += W1^T . relu(h)^T + b1 ----
    const unsigned short* w1b = w1p + i * 65536;
#pragma unroll
    for (int ks = 0; ks < 8; ks++) {
      short8 af[4], bf[4];
#pragma unroll
      for (int fm = 0; fm < 4; fm++)
        af[fm] = *(const short8*)(w1b + (size_t)(ks*16 + w*4 + fm) * 512 + l*8);
#pragma unroll
      for (int fn = 0; fn < 4; fn++)
        bf[fn] = *(const short8*)(&act2[(size_t)(fn*16 + lr) * ACT_STRIDE + ks*32 + lq*8]);
#pragma unroll
      for (int fm = 0; fm < 4; fm++)
#pragma unroll
        for (int fn = 0; fn < 4; fn++)
          net[fm][fn] = __builtin_amdgcn_mfma_f32_16x16x32_bf16(af[fm], bf[fn], net[fm][fn], 0, 0, 0);
    }
#pragma unroll
    for (int fm = 0; fm < 4; fm++) {
      float4 bq = ((const float4*)(b1 + i*256))[w*16 + fm*4 + lq];
      float bb[4] = {bq.x, bq.y, bq.z, bq.w};
#pragma unroll
      for (int r = 0; r < 4; r++)
#pragma unroll
        for (int fn = 0; fn < 4; fn++) net[fm][fn][r] += bb[r];
    }
  }

  // ---- out = relu(net) @ Wout + bout ----
  float s[4] = {0.f, 0.f, 0.f, 0.f};
#pragma unroll
  for (int fm = 0; fm < 4; fm++) {
    float4 wq = ((const float4*)Wout)[w*16 + fm*4 + lq];
    float wv[4] = {wq.x, wq.y, wq.z, wq.w};
#pragma unroll
    for (int r = 0; r < 4; r++)
#pragma unroll
      for (int fn = 0; fn < 4; fn++) s[fn] += fmaxf(net[fm][fn][r], 0.f) * wv[r];
  }
#pragma unroll
  for (int fn = 0; fn < 4; fn++) {
    s[fn] += __shfl_xor(s[fn], 16);
    s[fn] += __shfl_xor(s[fn], 32);
  }
  if (tid < 64) obuf[tid] = 0.f;
  __syncthreads();
  if (lq == 0) {
#pragma unroll
    for (int fn = 0; fn < 4; fn++) atomicAdd(&obuf[fn*16 + lr], s[fn]);
  }
  __syncthreads();
  if (tid < 64) out[ptile + tid] = obuf[tid] + bout[0];
}

extern "C" void kernel_launch(void* const* d_in, const int* in_sizes, int n_in,
                              void* d_out, int out_size, void* d_ws, size_t ws_size,
                              hipStream_t stream) {
  const float* p      = (const float*)d_in[0];
  const float* c_grid = (const float*)d_in[1];
  const float* c_xy   = (const float*)d_in[2];
  const float* c_yz   = (const float*)d_in[3];
  const float* c_xz   = (const float*)d_in[4];
  const float* Wp     = (const float*)d_in[5];
  const float* bp     = (const float*)d_in[6];
  const float* Wc     = (const float*)d_in[7];
  const float* bc     = (const float*)d_in[8];
  const float* W0     = (const float*)d_in[9];
  const float* b0     = (const float*)d_in[10];
  const float* W1     = (const float*)d_in[11];
  const float* b1     = (const float*)d_in[12];
  const float* Wout   = (const float*)d_in[13];
  const float* bout   = (const float*)d_in[14];

  char* ws = (char*)d_ws;
  unsigned short* wcp = (unsigned short*)(ws + OFF_WCP);
  unsigned short* w0p = (unsigned short*)(ws + OFF_W0P);
  unsigned short* w1p = (unsigned short*)(ws + OFF_W1P);
  unsigned short* gt  = (unsigned short*)(ws + OFF_GT);
  unsigned short* pt  = (unsigned short*)(ws + OFF_PT);
  float* out = (float*)d_out;

  prep<<<4480, 256, 0, stream>>>(Wc, W0, W1, c_grid, c_xy, c_yz, c_xz,
                                 wcp, w0p, w1p, gt, pt);
  mlp<<<MTOT / 64, 256, 0, stream>>>(p, Wp, bp, bc, b0, b1, Wout, bout,
                                     wcp, w0p, w1p, gt, pt, out);
}